// Round 4
// baseline (97.860 us; speedup 1.0000x reference)
//
#include <hip/hip_runtime.h>

#define NUM_K 64
#define CDIM 32
#define HW 16384          // 128*128
#define NPTS 1048576      // 64*128*128
#define NELEMD 33554432.0 // 64*32*128*128

// numpy pairwise sum of squares, n=32 contiguous: 8 accumulators + fixed tree.
// Products must round fp32 individually (contract off, plain mul).
__device__ __forceinline__ float np_sumsq32(const float* v) {
#pragma clang fp contract(off)
    float r[8];
    #pragma unroll
    for (int j = 0; j < 8; ++j) {
        float p0 = v[j] * v[j];
        float p1 = v[j + 8] * v[j + 8];
        float p2 = v[j + 16] * v[j + 16];
        float p3 = v[j + 24] * v[j + 24];
        r[j] = ((p0 + p1) + p2) + p3;
    }
    return ((r[0] + r[1]) + (r[2] + r[3])) + ((r[4] + r[5]) + (r[6] + r[7]));
}

// Prepass: B[k] = np.sum(emb*emb, axis=1) in numpy's fp32 order -> global scratch,
// so the main loop reads it via s_load (SGPR operand) instead of per-k LDS reads.
__global__ void vq_prep(const float* __restrict__ emb, float* __restrict__ Bg) {
#pragma clang fp contract(off)
    int k = threadIdx.x;
    if (k < NUM_K) {
        float e[CDIM];
        #pragma unroll
        for (int c = 0; c < CDIM; ++c) e[c] = emb[k * CDIM + c];
        Bg[k] = np_sumsq32(e);
    }
}

__global__ __launch_bounds__(256) void vq_main(const float* __restrict__ x,
                                               const float* __restrict__ emb,
                                               const float* __restrict__ Bg,
                                               float* __restrict__ outq,
                                               double* __restrict__ ws) {
#pragma clang fp contract(off)
    __shared__ float sET[CDIM][NUM_K];  // transposed codebook for the divergent gather
    __shared__ float sRed[4];

    const int t = threadIdx.x;
    // Conflict-free staging: thread i writes flat LDS addr i (bank i%32, no conflict);
    // the transposed global read is uncoalesced but totals 8 KB (L2-resident).
    #pragma unroll
    for (int i = t; i < NUM_K * CDIM; i += 256) {
        int c = i >> 6, k = i & 63;
        ((float*)sET)[i] = emb[k * CDIM + c];   // sET[c][k], flat = c*64+k = i
    }
    __syncthreads();

    const int p = blockIdx.x * 256 + t;
    const int b = p >> 14;            // point / (128*128)
    const int rem = p & (HW - 1);
    const size_t base = (size_t)b * (CDIM * HW) + rem;
    const float* xp = x + base;

    float xv[CDIM];
    #pragma unroll
    for (int c = 0; c < CDIM; ++c) xv[c] = xp[(size_t)c * HW];  // coalesced across lanes

    const float A = np_sumsq32(xv);   // np.sum(x*x, axis=1), numpy fp32 order

    // d_k = fp32( fp32(A + B_k) - 2*C_k ); C_k = ascending-c sequential fp32 FMA chain.
    // fmaf(-2, acc, t1) == t1 - (acc+acc) bitwise (2*acc exact, single rounding).
    // Strict < ascending k = first-min, matching np.argmin on the quantized grid.
    float best = 3.4028235e38f;
    int bi = 0;
    #pragma unroll 4
    for (int k = 0; k < NUM_K; ++k) {
        const float* __restrict__ ek = emb + k * CDIM;  // uniform -> s_load -> SGPR
        float acc = 0.f;
        #pragma unroll
        for (int c = 0; c < CDIM; ++c)
            acc = fmaf(xv[c], ek[c], acc);
        float t1 = A + Bg[k];                           // Bg uniform -> s_load
        float d  = fmaf(-2.f, acc, t1);
        if (d < best) { best = d; bi = k; }
    }

    // Gather winner row + store + loss partial. sET[c][bi]: bank = bi%32 (random,
    // avg ~4-way conflict -- the only remaining LDS hotspot, inherent to the gather).
    float* op = outq + base;
    float lsum = 0.f;
    #pragma unroll
    for (int c = 0; c < CDIM; ++c) {
        float q = sET[c][bi];
        op[(size_t)c * HW] = q;        // coalesced across lanes
        float diff = q - xv[c];
        lsum = fmaf(diff, diff, lsum);
    }

    #pragma unroll
    for (int off = 32; off > 0; off >>= 1)
        lsum += __shfl_down(lsum, off, 64);
    const int wid = t >> 6;
    if ((t & 63) == 0) sRed[wid] = lsum;
    __syncthreads();
    if (t == 0) {
        double bs = (double)sRed[0] + (double)sRed[1] + (double)sRed[2] + (double)sRed[3];
        atomicAdd(ws, bs);
    }
}

__global__ void vq_finish(const double* __restrict__ ws, float* __restrict__ loss) {
    loss[0] = (float)(1.25 * ws[0] / NELEMD);
}

extern "C" void kernel_launch(void* const* d_in, const int* in_sizes, int n_in,
                              void* d_out, int out_size, void* d_ws, size_t ws_size,
                              hipStream_t stream) {
    const float* x = (const float*)d_in[0];
    const float* emb = (const float*)d_in[1];
    float* out = (float*)d_out;
    // ws layout: [0..7] double loss accumulator, [16..272) float B[64]
    double* acc = (double*)d_ws;
    float* Bg = (float*)((char*)d_ws + 16);

    hipMemsetAsync(d_ws, 0, sizeof(double), stream);  // zero accumulator every call
    vq_prep<<<1, 64, 0, stream>>>(emb, Bg);
    vq_main<<<NPTS / 256, 256, 0, stream>>>(x, emb, Bg, out + 1, acc);
    vq_finish<<<1, 1, 0, stream>>>(acc, out);
}